// Round 8
// baseline (685.545 us; speedup 1.0000x reference)
//
#include <hip/hip_runtime.h>
#include <hip/hip_fp8.h>

#define NN 6144
#define F1 128
#define SSCALE 512.0f
#define SSCALE_INV (1.0f / 512.0f)
#define CWAVES 8
#define CKC (NN / CWAVES)  // 768
#define BSTRIDE 65

typedef __attribute__((ext_vector_type(4))) float f32x4;

// pack 4 floats -> 4 fp8 e4m3 bytes
__device__ __forceinline__ unsigned int pack4_fp8(float a, float b, float c, float d) {
#if __has_builtin(__builtin_amdgcn_cvt_pk_fp8_f32)
  int v = __builtin_amdgcn_cvt_pk_fp8_f32(a, b, 0, false);
  v = __builtin_amdgcn_cvt_pk_fp8_f32(c, d, v, true);
  return (unsigned int)v;
#else
  __hip_fp8_e4m3 qa(a), qb(b), qc(c), qd(d);
  return (unsigned)qa.__x | ((unsigned)qb.__x << 8) | ((unsigned)qc.__x << 16) |
         ((unsigned)qd.__x << 24);
#endif
}

__device__ __forceinline__ unsigned char f2fp8(float a) {
#if __has_builtin(__builtin_amdgcn_cvt_pk_fp8_f32)
  return (unsigned char)(__builtin_amdgcn_cvt_pk_fp8_f32(a, a, 0, false) & 0xFF);
#else
  __hip_fp8_e4m3 q(a);
  return q.__x;
#endif
}

// ---------------------------------------------------------------- prep
__global__ __launch_bounds__(128) void prep_kernel(
    const float* __restrict__ x5, const float* __restrict__ x0,
    const float* __restrict__ W_gat, const float* __restrict__ b_gat,
    const float* __restrict__ W_lin, const float* __restrict__ b_lin,
    float* __restrict__ hT, float* __restrict__ sq,
    float* __restrict__ Tx0, unsigned char* __restrict__ XT0) {
  int i = blockIdx.x;
  int t = threadIdx.x;
  __shared__ float xs[64];
  __shared__ float x5s[3];
  __shared__ float hs[6];
  if (t < 3) x5s[t] = x5[i * 3 + t];
  if (t < 64) xs[t] = x0[(size_t)i * 64 + t];
  __syncthreads();
  if (t < 6) {
    float a = b_gat[t];
#pragma unroll
    for (int k = 0; k < 3; k++) a += x5s[k] * W_gat[k * 6 + t];
    a = fmaxf(a, 0.f);
    hs[t] = a;
    hT[(size_t)t * NN + i] = a;
  }
  __syncthreads();
  if (t == 0) {
    float s = 0.f;
#pragma unroll
    for (int k = 0; k < 6; k++) s += hs[k] * hs[k];
    sq[i] = s;
  }
  float a = b_lin[t];
#pragma unroll 16
  for (int k = 0; k < 64; k++) a += xs[k] * W_lin[k * 128 + t];
  a = fmaxf(a, 0.f);
  Tx0[(size_t)i * F1 + t] = a;
  XT0[(size_t)t * NN + i] = f2fp8(a);
}

// ---------------------------------------------------------------- deg (dinv only, no P write)
__global__ __launch_bounds__(256) void deg_kernel(
    const float* __restrict__ hT, const float* __restrict__ sq,
    float* __restrict__ dinv) {
  int i = blockIdx.x;
  int t = threadIdx.x;
  float h0 = hT[i], h1 = hT[NN + i], h2 = hT[2 * NN + i];
  float h3 = hT[3 * NN + i], h4 = hT[4 * NN + i], h5 = hT[5 * NN + i];
  float si = sq[i];
  float acc = 0.f;
  for (int j = t; j < NN; j += 256) {
    float dot = h0 * hT[j] + h1 * hT[NN + j] + h2 * hT[2 * NN + j] +
                h3 * hT[3 * NN + j] + h4 * hT[4 * NN + j] + h5 * hT[5 * NN + j];
    float d = si + sq[j] - 2.f * dot;
    float p = __expf(-0.5f * d);
    if (j != i) acc += p;
  }
  __shared__ float red[256];
  red[t] = acc;
  __syncthreads();
  for (int s = 128; s > 0; s >>= 1) {
    if (t < s) red[t] += red[t + s];
    __syncthreads();
  }
  if (t == 0) {
    float deg = red[0];
    dinv[i] = deg > 0.f ? rsqrtf(deg) : 0.f;
  }
}

// ---------------------------------------------------------------- pwrite (P matrix, runs LAST)
__global__ __launch_bounds__(256) void pwrite_kernel(
    const float* __restrict__ hT, const float* __restrict__ sq,
    float* __restrict__ P) {
  int i = blockIdx.x;
  int t = threadIdx.x;
  float h0 = hT[i], h1 = hT[NN + i], h2 = hT[2 * NN + i];
  float h3 = hT[3 * NN + i], h4 = hT[4 * NN + i], h5 = hT[5 * NN + i];
  float si = sq[i];
  float* Pr = P + (size_t)i * NN;
  for (int j = t; j < NN; j += 256) {
    float dot = h0 * hT[j] + h1 * hT[NN + j] + h2 * hT[2 * NN + j] +
                h3 * hT[3 * NN + j] + h4 * hT[4 * NN + j] + h5 * hT[5 * NN + j];
    float d = si + sq[j] - 2.f * dot;
    Pr[j] = __expf(-0.5f * d);
  }
}

// ---------------------------------------------------------------- smat (fp8, scaled by 512)
__global__ __launch_bounds__(256) void smat_kernel(
    const float* __restrict__ hT, const float* __restrict__ sq,
    const float* __restrict__ dinv, unsigned int* __restrict__ S32) {
  int i = blockIdx.x;
  int t = threadIdx.x;
  float h0 = hT[i], h1 = hT[NN + i], h2 = hT[2 * NN + i];
  float h3 = hT[3 * NN + i], h4 = hT[4 * NN + i], h5 = hT[5 * NN + i];
  float si = sq[i];
  float dis = -SSCALE * dinv[i];
  unsigned int* Sr = S32 + (size_t)i * (NN / 4);
  for (int j4 = t; j4 < NN / 4; j4 += 256) {
    int j = j4 * 4;
    float4 qv = *(const float4*)(sq + j);
    float4 dj = *(const float4*)(dinv + j);
    float4 v0 = *(const float4*)(hT + j);
    float4 v1 = *(const float4*)(hT + NN + j);
    float4 v2 = *(const float4*)(hT + 2 * NN + j);
    float4 v3 = *(const float4*)(hT + 3 * NN + j);
    float4 v4 = *(const float4*)(hT + 4 * NN + j);
    float4 v5 = *(const float4*)(hT + 5 * NN + j);
    float s[4];
#pragma unroll
    for (int m = 0; m < 4; m++) {
      float dot = h0 * ((const float*)&v0)[m] + h1 * ((const float*)&v1)[m] +
                  h2 * ((const float*)&v2)[m] + h3 * ((const float*)&v3)[m] +
                  h4 * ((const float*)&v4)[m] + h5 * ((const float*)&v5)[m];
      float d = si + ((const float*)&qv)[m] - 2.f * dot;
      float p = __expf(-0.5f * d);
      s[m] = dis * p * ((const float*)&dj)[m];
      if (j + m == i) s[m] = 0.f;
    }
    Sr[j4] = pack4_fp8(s[0], s[1], s[2], s[3]);
  }
}

// ---------------------------------------------------------------- chain step (fused gemm+finalize)
// 192 blocks x 512 thr (8 waves). Block owns rows [32b, 32b+32) x all 128 cols,
// FULL K: wave w covers k in [w*768, (w+1)*768). In-register MFMA accumulate,
// one-sync LDS gather-sum across waves, recurrence, Tx f32 + XT fp8 writes.
__global__ __launch_bounds__(512) void chain_kernel(
    const unsigned char* __restrict__ S, const unsigned char* __restrict__ XTin,
    const float4* __restrict__ prevprev, float4* __restrict__ TxOut,
    unsigned int* __restrict__ XT8, int dsub) {
  __shared__ float buf[CWAVES][64 * BSTRIDE];  // 133 KB
  int t = threadIdx.x;
  int w = t >> 6;
  int l = t & 63;
  int lr = l & 15;
  int lg = l >> 4;
  int row0 = blockIdx.x * 32;
  int k0 = w * CKC;

  f32x4 acc[2][8];
#pragma unroll
  for (int rb = 0; rb < 2; rb++)
#pragma unroll
    for (int n = 0; n < 8; n++) acc[rb][n] = (f32x4){0.f, 0.f, 0.f, 0.f};

  const unsigned char* Ab = S + (size_t)(row0 + lr) * NN + k0 + lg * 8;
  const unsigned char* Bb = XTin + (size_t)lr * NN + k0 + lg * 8;

#pragma unroll 2
  for (int kk = 0; kk < CKC; kk += 32) {
    long a0 = *(const long*)(Ab + kk);
    long a1 = *(const long*)(Ab + (size_t)16 * NN + kk);
#pragma unroll
    for (int n = 0; n < 8; n++) {
      long b = *(const long*)(Bb + (size_t)n * 16 * NN + kk);
      acc[0][n] = __builtin_amdgcn_mfma_f32_16x16x32_fp8_fp8(a0, b, acc[0][n], 0, 0, 0);
      acc[1][n] = __builtin_amdgcn_mfma_f32_16x16x32_fp8_fp8(a1, b, acc[1][n], 0, 0, 0);
    }
  }

  // stash: value (rb,n,r) of lane l -> buf[w][l*65 + (rb*8+n)*4 + r]
  // (C/D layout: row = rb*16 + lg*4 + r, col = n*16 + lr)
  float* mybuf = &buf[w][l * BSTRIDE];
#pragma unroll
  for (int rb = 0; rb < 2; rb++)
#pragma unroll
    for (int n = 0; n < 8; n++) {
      int idx = (rb * 8 + n) * 4;
      mybuf[idx + 0] = acc[rb][n][0];
      mybuf[idx + 1] = acc[rb][n][1];
      mybuf[idx + 2] = acc[rb][n][2];
      mybuf[idx + 3] = acc[rb][n][3];
    }
  __syncthreads();

  // gather-sum 8 wave-partials; thread handles elements 4t..4t+3 and +2048
  float4 gh[2];
#pragma unroll
  for (int h = 0; h < 2; h++) {
    int e0 = 4 * t + h * 2048;
    int row = e0 >> 7;        // 0..31
    int col0 = e0 & 127;      // multiple of 4
    int srb = row >> 4, slg = (row >> 2) & 3, sr = row & 3;
    float gg[4];
#pragma unroll
    for (int j = 0; j < 4; j++) {
      int col = col0 + j;
      int lad = (slg * 16 + (col & 15)) * BSTRIDE + (srb * 8 + (col >> 4)) * 4 + sr;
      float s = 0.f;
#pragma unroll
      for (int w2 = 0; w2 < CWAVES; w2++) s += buf[w2][lad];
      gg[j] = s;
    }
    float sc = dsub ? (2.f * SSCALE_INV) : SSCALE_INV;
    float4 g;
    g.x = gg[0] * sc; g.y = gg[1] * sc; g.z = gg[2] * sc; g.w = gg[3] * sc;
    size_t oidx = (size_t)row0 * 32 + t + h * 512;
    if (dsub) {
      float4 q = prevprev[oidx];
      g.x -= q.x; g.y -= q.y; g.z -= q.z; g.w -= q.w;
    }
    TxOut[oidx] = g;
    gh[h] = g;
  }
  __syncthreads();  // all gathers done before overwriting buf[0]

  // transpose staging for fp8 XT: gb[row][col], 32x130 fits in buf[0] exactly
  float* gb = &buf[0][0];
#pragma unroll
  for (int h = 0; h < 2; h++) {
    int e0 = 4 * t + h * 2048;
    int row = e0 >> 7;
    int col0 = e0 & 127;
    gb[row * 130 + col0 + 0] = gh[h].x;
    gb[row * 130 + col0 + 1] = gh[h].y;
    gb[row * 130 + col0 + 2] = gh[h].z;
    gb[row * 130 + col0 + 3] = gh[h].w;
  }
  __syncthreads();
#pragma unroll
  for (int u = t; u < 1024; u += 512) {
    int c = u >> 3, rq = u & 7;
    unsigned int pk = pack4_fp8(gb[(rq * 4 + 0) * 130 + c], gb[(rq * 4 + 1) * 130 + c],
                                gb[(rq * 4 + 2) * 130 + c], gb[(rq * 4 + 3) * 130 + c]);
    XT8[((size_t)c * NN + row0 + rq * 4) >> 2] = pk;
  }
}

// ---------------------------------------------------------------- epilogue
__global__ __launch_bounds__(256) void out_kernel(
    const float* __restrict__ Tx, const float* __restrict__ Wcat,
    const float* __restrict__ b3, const float* __restrict__ b6,
    const float* __restrict__ b9,
    const float* __restrict__ Wl, const float* __restrict__ bl,
    float* __restrict__ x_out, float* __restrict__ last_out) {
  __shared__ float WS[128 * 48];
  __shared__ float TxS[32][129];
  __shared__ float lo[32][48];
  __shared__ float lg[32][16];
  __shared__ float le[32][16];
  __shared__ float WlS[48 * 16];
  __shared__ float blS[16];
  int t = threadIdx.x;
  int row0 = blockIdx.x * 32;
  int rg = t >> 4;
  int cg = t & 15;
  float acc[2][3] = {{0.f, 0.f, 0.f}, {0.f, 0.f, 0.f}};
  for (int i = t; i < 768; i += 256) WlS[i] = Wl[i];
  if (t < 16) blS[t] = bl[t];
  for (int k = 0; k < 9; k++) {
    for (int i = t; i < 6144; i += 256) WS[i] = Wcat[k * 6144 + i];
    for (int i = t; i < 4096; i += 256) {
      int r = i >> 7, j = i & 127;
      TxS[r][j] = Tx[((size_t)k * NN + row0 + r) * F1 + j];
    }
    __syncthreads();
#pragma unroll 4
    for (int j = 0; j < 128; j++) {
      float t0 = TxS[2 * rg][j], t1 = TxS[2 * rg + 1][j];
      const float* wp = &WS[j * 48 + 3 * cg];
      float w0 = wp[0], w1 = wp[1], w2 = wp[2];
      acc[0][0] += t0 * w0; acc[0][1] += t0 * w1; acc[0][2] += t0 * w2;
      acc[1][0] += t1 * w0; acc[1][1] += t1 * w1; acc[1][2] += t1 * w2;
    }
    __syncthreads();
  }
#pragma unroll
  for (int rr = 0; rr < 2; rr++) {
    int r = 2 * rg + rr;
#pragma unroll
    for (int cc = 0; cc < 3; cc++) {
      int c = 3 * cg + cc;
      float bias = c < 16 ? b3[c] : (c < 32 ? b6[c - 16] : b9[c - 32]);
      float v = acc[rr][cc] + bias;
      lo[r][c] = v;
      last_out[(size_t)(row0 + r) * 48 + c] = v;
    }
  }
  __syncthreads();
#pragma unroll
  for (int s = 0; s < 2; s++) {
    int idx = t + 256 * s;
    int r = idx >> 4, c = idx & 15;
    float lgt = blS[c];
#pragma unroll 8
    for (int j = 0; j < 48; j++) lgt += lo[r][j] * WlS[j * 16 + c];
    lg[r][c] = lgt;
  }
  __syncthreads();
#pragma unroll
  for (int s = 0; s < 2; s++) {
    int idx = t + 256 * s;
    int r = idx >> 4, c = idx & 15;
    float mx = lg[r][0];
#pragma unroll
    for (int j = 1; j < 16; j++) mx = fmaxf(mx, lg[r][j]);
    le[r][c] = __expf(lg[r][c] - mx);
  }
  __syncthreads();
#pragma unroll
  for (int s = 0; s < 2; s++) {
    int idx = t + 256 * s;
    int r = idx >> 4, c = idx & 15;
    float sum = 0.f;
#pragma unroll
    for (int j = 0; j < 16; j++) sum += le[r][j];
    x_out[(size_t)(row0 + r) * 16 + c] = le[r][c] / sum;
  }
}

// ---------------------------------------------------------------- misc copies + Wcat build
__global__ __launch_bounds__(256) void copy_kernel(
    const int* __restrict__ tr, const int* __restrict__ val,
    const float* __restrict__ x0, float* __restrict__ tr_out,
    float* __restrict__ val_out, float* __restrict__ x0_out,
    const float* __restrict__ W3, const float* __restrict__ W6,
    const float* __restrict__ W9, float* __restrict__ Wcat) {
  int i = blockIdx.x * 256 + threadIdx.x;
  if (i < 4000) tr_out[i] = (float)tr[i];
  if (i < 1000) val_out[i] = (float)val[i];
  if (i < NN * 64) x0_out[i] = x0[i];
  if (i < 9 * 128 * 48) {
    int c = i % 48;
    int j = (i / 48) % 128;
    int k = i / (48 * 128);
    float v = 0.f;
    if (c < 16) {
      if (k < 3) v = W3[(k * 128 + j) * 16 + c];
    } else if (c < 32) {
      if (k < 6) v = W6[(k * 128 + j) * 16 + (c - 16)];
    } else {
      v = W9[(k * 128 + j) * 16 + (c - 32)];
    }
    Wcat[i] = v;
  }
}

extern "C" void kernel_launch(void* const* d_in, const int* in_sizes, int n_in,
                              void* d_out, int out_size, void* d_ws, size_t ws_size,
                              hipStream_t stream) {
  const float* x5 = (const float*)d_in[0];
  const float* x0 = (const float*)d_in[1];
  const int* tr = (const int*)d_in[2];
  const int* val = (const int*)d_in[3];
  const float* W_gat = (const float*)d_in[4];
  const float* b_gat = (const float*)d_in[5];
  const float* W_lin = (const float*)d_in[6];
  const float* b_lin = (const float*)d_in[7];
  const float* W3 = (const float*)d_in[8];
  const float* b3 = (const float*)d_in[9];
  const float* W6 = (const float*)d_in[10];
  const float* b6 = (const float*)d_in[11];
  const float* W9 = (const float*)d_in[12];
  const float* b9 = (const float*)d_in[13];
  const float* Wl = (const float*)d_in[14];
  const float* bl = (const float*)d_in[15];

  float* out = (float*)d_out;
  float* x_out = out;
  float* tr_out = x_out + (size_t)NN * 16;
  float* val_out = tr_out + 4000;
  float* P = val_out + 1000;
  float* last_out = P + (size_t)NN * NN;
  float* x0_out = last_out + (size_t)NN * 48;

  char* w = (char*)d_ws;
  unsigned char* Sb = (unsigned char*)w;    w += (size_t)NN * NN;
  float* Tx = (float*)w;                    w += (size_t)9 * NN * F1 * 4;
  unsigned char* XTa = (unsigned char*)w;   w += (size_t)NN * F1;
  unsigned char* XTb = (unsigned char*)w;   w += (size_t)NN * F1;
  float* hT = (float*)w;                    w += (size_t)6 * NN * 4;
  float* sq = (float*)w;                    w += (size_t)NN * 4;
  float* dinv = (float*)w;                  w += (size_t)NN * 4;
  float* Wcat = (float*)w;                  w += (size_t)9 * 128 * 48 * 4;

  prep_kernel<<<NN, 128, 0, stream>>>(x5, x0, W_gat, b_gat, W_lin, b_lin, hT, sq,
                                      Tx, XTa);
  deg_kernel<<<NN, 256, 0, stream>>>(hT, sq, dinv);
  smat_kernel<<<NN, 256, 0, stream>>>(hT, sq, dinv, (unsigned int*)Sb);
  copy_kernel<<<1536, 256, 0, stream>>>(tr, val, x0, tr_out, val_out, x0_out,
                                        W3, W6, W9, Wcat);

  unsigned char* xin = XTa;
  unsigned char* xout = XTb;
  for (int k = 1; k <= 8; k++) {
    chain_kernel<<<192, 512, 0, stream>>>(
        Sb, xin,
        (const float4*)(Tx + (size_t)(k >= 2 ? k - 2 : 0) * NN * F1),
        (float4*)(Tx + (size_t)k * NN * F1),
        (unsigned int*)xout, k >= 2 ? 1 : 0);
    unsigned char* tmp = xin; xin = xout; xout = tmp;
  }

  out_kernel<<<192, 256, 0, stream>>>(Tx, Wcat, b3, b6, b9, Wl, bl, x_out,
                                      last_out);
  pwrite_kernel<<<NN, 256, 0, stream>>>(hT, sq, P);
}

// Round 9
// 462.464 us; speedup vs baseline: 1.4824x; 1.4824x over previous
//
#include <hip/hip_runtime.h>

#define NN 6144
#define F1 128
#define KSPLIT 12
#define KC 512
#define BK 64
#define LDK 72  // padded LDS row stride (16B-aligned, breaks bank conflicts)

typedef __attribute__((ext_vector_type(8))) short short8_t;
typedef __attribute__((ext_vector_type(4))) float f32x4;

__device__ __forceinline__ unsigned short f2bf(float f) {
  unsigned int u = __float_as_uint(f);
  unsigned int r = (u + 0x7fffu + ((u >> 16) & 1u)) >> 16;
  return (unsigned short)r;
}

// ---------------------------------------------------------------- prep
__global__ __launch_bounds__(128) void prep_kernel(
    const float* __restrict__ x5, const float* __restrict__ x0,
    const float* __restrict__ W_gat, const float* __restrict__ b_gat,
    const float* __restrict__ W_lin, const float* __restrict__ b_lin,
    float* __restrict__ hT, float* __restrict__ sq,
    float* __restrict__ Tx0, unsigned short* __restrict__ XT0) {
  int i = blockIdx.x;
  int t = threadIdx.x;
  __shared__ float xs[64];
  __shared__ float x5s[3];
  __shared__ float hs[6];
  if (t < 3) x5s[t] = x5[i * 3 + t];
  if (t < 64) xs[t] = x0[(size_t)i * 64 + t];
  __syncthreads();
  if (t < 6) {
    float a = b_gat[t];
#pragma unroll
    for (int k = 0; k < 3; k++) a += x5s[k] * W_gat[k * 6 + t];
    a = fmaxf(a, 0.f);
    hs[t] = a;
    hT[(size_t)t * NN + i] = a;
  }
  __syncthreads();
  if (t == 0) {
    float s = 0.f;
#pragma unroll
    for (int k = 0; k < 6; k++) s += hs[k] * hs[k];
    sq[i] = s;
  }
  float a = b_lin[t];
#pragma unroll 16
  for (int k = 0; k < 64; k++) a += xs[k] * W_lin[k * 128 + t];
  a = fmaxf(a, 0.f);
  Tx0[(size_t)i * F1 + t] = a;
  XT0[(size_t)t * NN + i] = f2bf(a);
}

// ---------------------------------------------------------------- prob
__global__ __launch_bounds__(256) void prob_kernel(
    const float* __restrict__ hT, const float* __restrict__ sq,
    float* __restrict__ P, float* __restrict__ dinv) {
  int i = blockIdx.x;
  int t = threadIdx.x;
  float h0 = hT[i], h1 = hT[NN + i], h2 = hT[2 * NN + i];
  float h3 = hT[3 * NN + i], h4 = hT[4 * NN + i], h5 = hT[5 * NN + i];
  float si = sq[i];
  float acc = 0.f;
  float* Pr = P + (size_t)i * NN;
  for (int j = t; j < NN; j += 256) {
    float dot = h0 * hT[j] + h1 * hT[NN + j] + h2 * hT[2 * NN + j] +
                h3 * hT[3 * NN + j] + h4 * hT[4 * NN + j] + h5 * hT[5 * NN + j];
    float d = si + sq[j] - 2.f * dot;
    float p = __expf(-0.5f * d);
    Pr[j] = p;
    if (j != i) acc += p;
  }
  __shared__ float red[256];
  red[t] = acc;
  __syncthreads();
  for (int s = 128; s > 0; s >>= 1) {
    if (t < s) red[t] += red[t + s];
    __syncthreads();
  }
  if (t == 0) {
    float deg = red[0];
    dinv[i] = deg > 0.f ? rsqrtf(deg) : 0.f;
  }
}

// ---------------------------------------------------------------- smat (bf16)
__global__ __launch_bounds__(256) void smat_kernel(
    const float* __restrict__ hT, const float* __restrict__ sq,
    const float* __restrict__ dinv, unsigned short* __restrict__ Sb) {
  int i = blockIdx.x;
  int t = threadIdx.x;
  float h0 = hT[i], h1 = hT[NN + i], h2 = hT[2 * NN + i];
  float h3 = hT[3 * NN + i], h4 = hT[4 * NN + i], h5 = hT[5 * NN + i];
  float si = sq[i];
  float di = dinv[i];
  unsigned short* Sr = Sb + (size_t)i * NN;
  for (int j = t; j < NN; j += 256) {
    float dot = h0 * hT[j] + h1 * hT[NN + j] + h2 * hT[2 * NN + j] +
                h3 * hT[3 * NN + j] + h4 * hT[4 * NN + j] + h5 * hT[5 * NN + j];
    float d = si + sq[j] - 2.f * dot;
    float p = __expf(-0.5f * d);
    float s = (j == i) ? 0.f : -(di * p * dinv[j]);
    Sr[j] = f2bf(s);
  }
}

// ---------------------------------------------------------------- gemm (LDS-tiled, split-K)
// grid 576 = (48 mb x 12 ks), block 256 (4 waves, 2x2); block tile 128x128,
// BK=64 staged in LDS (reg-staged, padded stride LDK=72). 2.25 blocks/CU.
__global__ __launch_bounds__(256) void gemm_kernel(
    const unsigned short* __restrict__ S, const unsigned short* __restrict__ XT,
    float* __restrict__ partial) {
  __shared__ unsigned short As[128 * LDK];
  __shared__ unsigned short Bs[128 * LDK];
  // bijective XCD swizzle: 576 = 8 XCDs x 72
  int orig = blockIdx.x;
  int wgid = (orig & 7) * 72 + (orig >> 3);
  int mb = wgid % 48;
  int ks = wgid / 48;
  int t = threadIdx.x;
  int w = t >> 6, l = t & 63;
  int wr = w >> 1, wc = w & 1;
  int lr = l & 15, lg = l >> 4;
  int row0 = mb * 128;
  int k0 = ks * KC;

  f32x4 acc[4][4];
#pragma unroll
  for (int a = 0; a < 4; a++)
#pragma unroll
    for (int b = 0; b < 4; b++) acc[a][b] = (f32x4){0.f, 0.f, 0.f, 0.f};

  for (int bk = 0; bk < KC; bk += BK) {
    // stage A(128x64) and B(128x64): thread handles 4 chunks of 16B each
#pragma unroll
    for (int c4 = 0; c4 < 4; c4++) {
      int c = t + c4 * 256;
      int row = c >> 3, ko = (c & 7) * 8;
      short8_t va = *(const short8_t*)(S + (size_t)(row0 + row) * NN + k0 + bk + ko);
      short8_t vb = *(const short8_t*)(XT + (size_t)row * NN + k0 + bk + ko);
      *(short8_t*)(&As[row * LDK + ko]) = va;
      *(short8_t*)(&Bs[row * LDK + ko]) = vb;
    }
    __syncthreads();
#pragma unroll
    for (int kk2 = 0; kk2 < BK; kk2 += 32) {
      short8_t af[4], bf[4];
#pragma unroll
      for (int i = 0; i < 4; i++) {
        af[i] = *(const short8_t*)(&As[(wr * 64 + i * 16 + lr) * LDK + kk2 + lg * 8]);
        bf[i] = *(const short8_t*)(&Bs[(wc * 64 + i * 16 + lr) * LDK + kk2 + lg * 8]);
      }
#pragma unroll
      for (int ar = 0; ar < 4; ar++)
#pragma unroll
        for (int bn = 0; bn < 4; bn++)
          acc[ar][bn] =
              __builtin_amdgcn_mfma_f32_16x16x32_bf16(af[ar], bf[bn], acc[ar][bn], 0, 0, 0);
    }
    __syncthreads();
  }

  // C/D layout: col = lane&15, row-in-16 = lg*4 + r
  float* pbase = partial + (size_t)ks * NN * F1;
#pragma unroll
  for (int ar = 0; ar < 4; ar++) {
    int rowo = row0 + wr * 64 + ar * 16 + lg * 4;
#pragma unroll
    for (int bn = 0; bn < 4; bn++) {
      int colo = wc * 64 + bn * 16 + lr;
#pragma unroll
      for (int r = 0; r < 4; r++)
        pbase[(size_t)(rowo + r) * F1 + colo] = acc[ar][bn][r];
    }
  }
}

// ---------------------------------------------------------------- finalize
// thread: rquad = t>>5 (4 consecutive rows), c4 = t&31 (4 features).
// Coalesced partial reads; XT written as 8B ushort4 (4 rows of one feature).
__global__ __launch_bounds__(256) void finalize_kernel(
    const float4* __restrict__ partial, const float4* __restrict__ prevprev,
    float4* __restrict__ TxOut, unsigned short* __restrict__ XTout, int dsub) {
  const int TOT4 = NN * F1 / 4;
  int t = threadIdx.x;
  int rquad = t >> 5, c4 = t & 31;
  int row0 = blockIdx.x * 32 + rquad * 4;
  float g[4][4];
#pragma unroll
  for (int rr = 0; rr < 4; rr++) {
    int fidx = (row0 + rr) * 32 + c4;
    float4 a = partial[fidx];
#pragma unroll
    for (int s = 1; s < KSPLIT; s++) {
      float4 p = partial[(size_t)s * TOT4 + fidx];
      a.x += p.x; a.y += p.y; a.z += p.z; a.w += p.w;
    }
    if (dsub) {
      float4 q = prevprev[fidx];
      a.x = 2.f * a.x - q.x; a.y = 2.f * a.y - q.y;
      a.z = 2.f * a.z - q.z; a.w = 2.f * a.w - q.w;
    }
    TxOut[fidx] = a;
    g[rr][0] = a.x; g[rr][1] = a.y; g[rr][2] = a.z; g[rr][3] = a.w;
  }
#pragma unroll
  for (int j = 0; j < 4; j++) {
    int f = c4 * 4 + j;
    ushort4 pk;
    pk.x = f2bf(g[0][j]); pk.y = f2bf(g[1][j]);
    pk.z = f2bf(g[2][j]); pk.w = f2bf(g[3][j]);
    *(ushort4*)(XTout + (size_t)f * NN + row0) = pk;
  }
}

// ---------------------------------------------------------------- epilogue
__global__ __launch_bounds__(256) void out_kernel(
    const float* __restrict__ Tx, const float* __restrict__ Wcat,
    const float* __restrict__ b3, const float* __restrict__ b6,
    const float* __restrict__ b9,
    const float* __restrict__ Wl, const float* __restrict__ bl,
    float* __restrict__ x_out, float* __restrict__ last_out) {
  __shared__ float WS[128 * 48];
  __shared__ float TxS[32][129];
  __shared__ float lo[32][48];
  __shared__ float lg[32][16];
  __shared__ float le[32][16];
  __shared__ float WlS[48 * 16];
  __shared__ float blS[16];
  int t = threadIdx.x;
  int row0 = blockIdx.x * 32;
  int rg = t >> 4;
  int cg = t & 15;
  float acc[2][3] = {{0.f, 0.f, 0.f}, {0.f, 0.f, 0.f}};
  for (int i = t; i < 768; i += 256) WlS[i] = Wl[i];
  if (t < 16) blS[t] = bl[t];
  for (int k = 0; k < 9; k++) {
    for (int i = t; i < 6144; i += 256) WS[i] = Wcat[k * 6144 + i];
    for (int i = t; i < 4096; i += 256) {
      int r = i >> 7, j = i & 127;
      TxS[r][j] = Tx[((size_t)k * NN + row0 + r) * F1 + j];
    }
    __syncthreads();
#pragma unroll 4
    for (int j = 0; j < 128; j++) {
      float t0 = TxS[2 * rg][j], t1 = TxS[2 * rg + 1][j];
      const float* wp = &WS[j * 48 + 3 * cg];
      float w0 = wp[0], w1 = wp[1], w2 = wp[2];
      acc[0][0] += t0 * w0; acc[0][1] += t0 * w1; acc[0][2] += t0 * w2;
      acc[1][0] += t1 * w0; acc[1][1] += t1 * w1; acc[1][2] += t1 * w2;
    }
    __syncthreads();
  }
#pragma unroll
  for (int rr = 0; rr < 2; rr++) {
    int r = 2 * rg + rr;
#pragma unroll
    for (int cc = 0; cc < 3; cc++) {
      int c = 3 * cg + cc;
      float bias = c < 16 ? b3[c] : (c < 32 ? b6[c - 16] : b9[c - 32]);
      float v = acc[rr][cc] + bias;
      lo[r][c] = v;
      last_out[(size_t)(row0 + r) * 48 + c] = v;
    }
  }
  __syncthreads();
#pragma unroll
  for (int s = 0; s < 2; s++) {
    int idx = t + 256 * s;
    int r = idx >> 4, c = idx & 15;
    float lgt = blS[c];
#pragma unroll 8
    for (int j = 0; j < 48; j++) lgt += lo[r][j] * WlS[j * 16 + c];
    lg[r][c] = lgt;
  }
  __syncthreads();
#pragma unroll
  for (int s = 0; s < 2; s++) {
    int idx = t + 256 * s;
    int r = idx >> 4, c = idx & 15;
    float mx = lg[r][0];
#pragma unroll
    for (int j = 1; j < 16; j++) mx = fmaxf(mx, lg[r][j]);
    le[r][c] = __expf(lg[r][c] - mx);
  }
  __syncthreads();
#pragma unroll
  for (int s = 0; s < 2; s++) {
    int idx = t + 256 * s;
    int r = idx >> 4, c = idx & 15;
    float sum = 0.f;
#pragma unroll
    for (int j = 0; j < 16; j++) sum += le[r][j];
    x_out[(size_t)(row0 + r) * 16 + c] = le[r][c] / sum;
  }
}

// ---------------------------------------------------------------- misc copies + Wcat build
__global__ __launch_bounds__(256) void copy_kernel(
    const int* __restrict__ tr, const int* __restrict__ val,
    const float* __restrict__ x0, float* __restrict__ tr_out,
    float* __restrict__ val_out, float* __restrict__ x0_out,
    const float* __restrict__ W3, const float* __restrict__ W6,
    const float* __restrict__ W9, float* __restrict__ Wcat) {
  int i = blockIdx.x * 256 + threadIdx.x;
  if (i < 4000) tr_out[i] = (float)tr[i];
  if (i < 1000) val_out[i] = (float)val[i];
  if (i < NN * 64) x0_out[i] = x0[i];
  if (i < 9 * 128 * 48) {
    int c = i % 48;
    int j = (i / 48) % 128;
    int k = i / (48 * 128);
    float v = 0.f;
    if (c < 16) {
      if (k < 3) v = W3[(k * 128 + j) * 16 + c];
    } else if (c < 32) {
      if (k < 6) v = W6[(k * 128 + j) * 16 + (c - 16)];
    } else {
      v = W9[(k * 128 + j) * 16 + (c - 32)];
    }
    Wcat[i] = v;
  }
}

extern "C" void kernel_launch(void* const* d_in, const int* in_sizes, int n_in,
                              void* d_out, int out_size, void* d_ws, size_t ws_size,
                              hipStream_t stream) {
  const float* x5 = (const float*)d_in[0];
  const float* x0 = (const float*)d_in[1];
  const int* tr = (const int*)d_in[2];
  const int* val = (const int*)d_in[3];
  const float* W_gat = (const float*)d_in[4];
  const float* b_gat = (const float*)d_in[5];
  const float* W_lin = (const float*)d_in[6];
  const float* b_lin = (const float*)d_in[7];
  const float* W3 = (const float*)d_in[8];
  const float* b3 = (const float*)d_in[9];
  const float* W6 = (const float*)d_in[10];
  const float* b6 = (const float*)d_in[11];
  const float* W9 = (const float*)d_in[12];
  const float* b9 = (const float*)d_in[13];
  const float* Wl = (const float*)d_in[14];
  const float* bl = (const float*)d_in[15];

  float* out = (float*)d_out;
  float* x_out = out;
  float* tr_out = x_out + (size_t)NN * 16;
  float* val_out = tr_out + 4000;
  float* P = val_out + 1000;
  float* last_out = P + (size_t)NN * NN;
  float* x0_out = last_out + (size_t)NN * 48;

  char* w = (char*)d_ws;
  unsigned short* Sb = (unsigned short*)w;  w += (size_t)NN * NN * 2;
  float* Tx = (float*)w;                    w += (size_t)9 * NN * F1 * 4;
  float* partial = (float*)w;               w += (size_t)KSPLIT * NN * F1 * 4;
  unsigned short* XTa = (unsigned short*)w; w += (size_t)NN * F1 * 2;
  unsigned short* XTb = (unsigned short*)w; w += (size_t)NN * F1 * 2;
  float* hT = (float*)w;                    w += (size_t)6 * NN * 4;
  float* sq = (float*)w;                    w += (size_t)NN * 4;
  float* dinv = (float*)w;                  w += (size_t)NN * 4;
  float* Wcat = (float*)w;                  w += (size_t)9 * 128 * 48 * 4;

  prep_kernel<<<NN, 128, 0, stream>>>(x5, x0, W_gat, b_gat, W_lin, b_lin, hT, sq,
                                      Tx, XTa);
  prob_kernel<<<NN, 256, 0, stream>>>(hT, sq, P, dinv);
  smat_kernel<<<NN, 256, 0, stream>>>(hT, sq, dinv, Sb);
  copy_kernel<<<1536, 256, 0, stream>>>(tr, val, x0, tr_out, val_out, x0_out,
                                        W3, W6, W9, Wcat);

  unsigned short* xin = XTa;
  unsigned short* xout = XTb;
  for (int k = 1; k <= 8; k++) {
    gemm_kernel<<<576, 256, 0, stream>>>(Sb, xin, partial);
    const float4* pp = (const float4*)(Tx + (size_t)(k >= 2 ? k - 2 : 0) * NN * F1);
    finalize_kernel<<<192, 256, 0, stream>>>((const float4*)partial, pp,
                                             (float4*)(Tx + (size_t)k * NN * F1),
                                             xout, k >= 2 ? 1 : 0);
    unsigned short* tmp = xin; xin = xout; xout = tmp;
  }

  out_kernel<<<192, 256, 0, stream>>>(Tx, Wcat, b3, b6, b9, Wl, bl, x_out,
                                      last_out);
}

// Round 10
// 427.782 us; speedup vs baseline: 1.6026x; 1.0811x over previous
//
#include <hip/hip_runtime.h>

#define NN 6144
#define F1 128
#define KSPLIT 16
#define KC 384
#define BK 64

typedef __attribute__((ext_vector_type(8))) short short8_t;
typedef __attribute__((ext_vector_type(4))) float f32x4;

__device__ __forceinline__ unsigned short f2bf(float f) {
  unsigned int u = __float_as_uint(f);
  unsigned int r = (u + 0x7fffu + ((u >> 16) & 1u)) >> 16;
  return (unsigned short)r;
}

// async global->LDS, 16B per lane; lds dest = base + lane*16 (wave-uniform base)
__device__ __forceinline__ void gload16(const void* g, void* l) {
  __builtin_amdgcn_global_load_lds(
      (const __attribute__((address_space(1))) unsigned int*)g,
      (__attribute__((address_space(3))) unsigned int*)l, 16, 0, 0);
}

// ---------------------------------------------------------------- prep
__global__ __launch_bounds__(128) void prep_kernel(
    const float* __restrict__ x5, const float* __restrict__ x0,
    const float* __restrict__ W_gat, const float* __restrict__ b_gat,
    const float* __restrict__ W_lin, const float* __restrict__ b_lin,
    float* __restrict__ hT, float* __restrict__ sq,
    float* __restrict__ Tx0, unsigned short* __restrict__ XT0) {
  int i = blockIdx.x;
  int t = threadIdx.x;
  __shared__ float xs[64];
  __shared__ float x5s[3];
  __shared__ float hs[6];
  if (t < 3) x5s[t] = x5[i * 3 + t];
  if (t < 64) xs[t] = x0[(size_t)i * 64 + t];
  __syncthreads();
  if (t < 6) {
    float a = b_gat[t];
#pragma unroll
    for (int k = 0; k < 3; k++) a += x5s[k] * W_gat[k * 6 + t];
    a = fmaxf(a, 0.f);
    hs[t] = a;
    hT[(size_t)t * NN + i] = a;
  }
  __syncthreads();
  if (t == 0) {
    float s = 0.f;
#pragma unroll
    for (int k = 0; k < 6; k++) s += hs[k] * hs[k];
    sq[i] = s;
  }
  float a = b_lin[t];
#pragma unroll 16
  for (int k = 0; k < 64; k++) a += xs[k] * W_lin[k * 128 + t];
  a = fmaxf(a, 0.f);
  Tx0[(size_t)i * F1 + t] = a;
  XT0[(size_t)t * NN + i] = f2bf(a);
}

// ---------------------------------------------------------------- prob
__global__ __launch_bounds__(256) void prob_kernel(
    const float* __restrict__ hT, const float* __restrict__ sq,
    float* __restrict__ P, float* __restrict__ dinv) {
  int i = blockIdx.x;
  int t = threadIdx.x;
  float h0 = hT[i], h1 = hT[NN + i], h2 = hT[2 * NN + i];
  float h3 = hT[3 * NN + i], h4 = hT[4 * NN + i], h5 = hT[5 * NN + i];
  float si = sq[i];
  float acc = 0.f;
  float* Pr = P + (size_t)i * NN;
  for (int j = t; j < NN; j += 256) {
    float dot = h0 * hT[j] + h1 * hT[NN + j] + h2 * hT[2 * NN + j] +
                h3 * hT[3 * NN + j] + h4 * hT[4 * NN + j] + h5 * hT[5 * NN + j];
    float d = si + sq[j] - 2.f * dot;
    float p = __expf(-0.5f * d);
    Pr[j] = p;
    if (j != i) acc += p;
  }
  __shared__ float red[256];
  red[t] = acc;
  __syncthreads();
  for (int s = 128; s > 0; s >>= 1) {
    if (t < s) red[t] += red[t + s];
    __syncthreads();
  }
  if (t == 0) {
    float deg = red[0];
    dinv[i] = deg > 0.f ? rsqrtf(deg) : 0.f;
  }
}

// ---------------------------------------------------------------- smat (bf16)
__global__ __launch_bounds__(256) void smat_kernel(
    const float* __restrict__ hT, const float* __restrict__ sq,
    const float* __restrict__ dinv, unsigned short* __restrict__ Sb) {
  int i = blockIdx.x;
  int t = threadIdx.x;
  float h0 = hT[i], h1 = hT[NN + i], h2 = hT[2 * NN + i];
  float h3 = hT[3 * NN + i], h4 = hT[4 * NN + i], h5 = hT[5 * NN + i];
  float si = sq[i];
  float di = dinv[i];
  unsigned short* Sr = Sb + (size_t)i * NN;
  for (int j = t; j < NN; j += 256) {
    float dot = h0 * hT[j] + h1 * hT[NN + j] + h2 * hT[2 * NN + j] +
                h3 * hT[3 * NN + j] + h4 * hT[4 * NN + j] + h5 * hT[5 * NN + j];
    float d = si + sq[j] - 2.f * dot;
    float p = __expf(-0.5f * d);
    float s = (j == i) ? 0.f : -(di * p * dinv[j]);
    Sr[j] = f2bf(s);
  }
}

// ---------------------------------------------------------------- gemm (gload_lds + swizzle)
// grid 768 = (48 mb x 16 ks), block 256 (4 waves 2x2); tile 128x128, BK=64.
// Linear LDS [128][64] + XOR-unit swizzle (store: src unit = ud^row&7;
// read: phys unit = u^(row&7)) -> 2-way banks, gload_lds-compatible.
__global__ __launch_bounds__(256, 3) void gemm_kernel(
    const unsigned short* __restrict__ S, const unsigned short* __restrict__ XT,
    float* __restrict__ partial) {
  __shared__ unsigned short As[128 * 64];
  __shared__ unsigned short Bs[128 * 64];
  // bijective XCD swizzle: 768 = 8 XCDs x 96
  int orig = blockIdx.x;
  int wgid = (orig & 7) * 96 + (orig >> 3);
  int mb = wgid % 48;
  int ks = wgid / 48;
  int t = threadIdx.x;
  int w = t >> 6, l = t & 63;
  int wr = w >> 1, wc = w & 1;
  int lr = l & 15, lg = l >> 4;
  int row0 = mb * 128;
  int k0 = ks * KC;

  // staging lane geometry: lane covers (r8 = l>>3, dest unit ud = l&7),
  // source unit us = ud ^ r8 (rows are 8-aligned per call -> row&7 == r8)
  int r8 = l >> 3;
  int us = (l & 7) ^ r8;
  const unsigned short* gA = S + (size_t)(row0 + w * 32 + r8) * NN + k0 + us * 8;
  const unsigned short* gB = XT + (size_t)(w * 32 + r8) * NN + k0 + us * 8;
  unsigned short* lA = As + (w * 32) * 64;
  unsigned short* lB = Bs + (w * 32) * 64;

  f32x4 acc[4][4];
#pragma unroll
  for (int a = 0; a < 4; a++)
#pragma unroll
    for (int b = 0; b < 4; b++) acc[a][b] = (f32x4){0.f, 0.f, 0.f, 0.f};

  for (int bk = 0; bk < KC; bk += BK) {
#pragma unroll
    for (int g = 0; g < 4; g++) {
      gload16(gA + (size_t)g * 8 * NN + bk, lA + g * 8 * 64);
      gload16(gB + (size_t)g * 8 * NN + bk, lB + g * 8 * 64);
    }
    __syncthreads();  // vmcnt(0) drain + barrier
#pragma unroll
    for (int kk2 = 0; kk2 < BK; kk2 += 32) {
      short8_t af[4], bf[4];
#pragma unroll
      for (int i = 0; i < 4; i++) {
        int ra = wr * 64 + i * 16 + lr;
        int rb = wc * 64 + i * 16 + lr;
        int u = (kk2 >> 3) + lg;
        af[i] = *(const short8_t*)(&As[ra * 64 + ((u ^ (ra & 7)) << 3)]);
        bf[i] = *(const short8_t*)(&Bs[rb * 64 + ((u ^ (rb & 7)) << 3)]);
      }
#pragma unroll
      for (int ar = 0; ar < 4; ar++)
#pragma unroll
        for (int bn = 0; bn < 4; bn++)
          acc[ar][bn] =
              __builtin_amdgcn_mfma_f32_16x16x32_bf16(af[ar], bf[bn], acc[ar][bn], 0, 0, 0);
    }
    __syncthreads();
  }

  // C/D layout: col = lane&15, row-in-16 = lg*4 + r
  float* pbase = partial + (size_t)ks * NN * F1;
#pragma unroll
  for (int ar = 0; ar < 4; ar++) {
    int rowo = row0 + wr * 64 + ar * 16 + lg * 4;
#pragma unroll
    for (int bn = 0; bn < 4; bn++) {
      int colo = wc * 64 + bn * 16 + lr;
#pragma unroll
      for (int r = 0; r < 4; r++)
        pbase[(size_t)(rowo + r) * F1 + colo] = acc[ar][bn][r];
    }
  }
}

// ---------------------------------------------------------------- finalize
__global__ __launch_bounds__(256) void finalize_kernel(
    const float4* __restrict__ partial, const float4* __restrict__ prevprev,
    float4* __restrict__ TxOut, unsigned short* __restrict__ XTout, int dsub) {
  const int TOT4 = NN * F1 / 4;
  int t = threadIdx.x;
  int rquad = t >> 5, c4 = t & 31;
  int row0 = blockIdx.x * 32 + rquad * 4;
  float g[4][4];
#pragma unroll
  for (int rr = 0; rr < 4; rr++) {
    int fidx = (row0 + rr) * 32 + c4;
    float4 a = partial[fidx];
#pragma unroll
    for (int s = 1; s < KSPLIT; s++) {
      float4 p = partial[(size_t)s * TOT4 + fidx];
      a.x += p.x; a.y += p.y; a.z += p.z; a.w += p.w;
    }
    if (dsub) {
      float4 q = prevprev[fidx];
      a.x = 2.f * a.x - q.x; a.y = 2.f * a.y - q.y;
      a.z = 2.f * a.z - q.z; a.w = 2.f * a.w - q.w;
    }
    TxOut[fidx] = a;
    g[rr][0] = a.x; g[rr][1] = a.y; g[rr][2] = a.z; g[rr][3] = a.w;
  }
#pragma unroll
  for (int j = 0; j < 4; j++) {
    int f = c4 * 4 + j;
    ushort4 pk;
    pk.x = f2bf(g[0][j]); pk.y = f2bf(g[1][j]);
    pk.z = f2bf(g[2][j]); pk.w = f2bf(g[3][j]);
    *(ushort4*)(XTout + (size_t)f * NN + row0) = pk;
  }
}

// ---------------------------------------------------------------- epilogue
__global__ __launch_bounds__(256) void out_kernel(
    const float* __restrict__ Tx, const float* __restrict__ Wcat,
    const float* __restrict__ b3, const float* __restrict__ b6,
    const float* __restrict__ b9,
    const float* __restrict__ Wl, const float* __restrict__ bl,
    float* __restrict__ x_out, float* __restrict__ last_out) {
  __shared__ float WS[128 * 48];
  __shared__ float TxS[32][129];
  __shared__ float lo[32][48];
  __shared__ float lg[32][16];
  __shared__ float le[32][16];
  __shared__ float WlS[48 * 16];
  __shared__ float blS[16];
  int t = threadIdx.x;
  int row0 = blockIdx.x * 32;
  int rg = t >> 4;
  int cg = t & 15;
  float acc[2][3] = {{0.f, 0.f, 0.f}, {0.f, 0.f, 0.f}};
  for (int i = t; i < 768; i += 256) WlS[i] = Wl[i];
  if (t < 16) blS[t] = bl[t];
  for (int k = 0; k < 9; k++) {
    for (int i = t; i < 6144; i += 256) WS[i] = Wcat[k * 6144 + i];
    for (int i = t; i < 4096; i += 256) {
      int r = i >> 7, j = i & 127;
      TxS[r][j] = Tx[((size_t)k * NN + row0 + r) * F1 + j];
    }
    __syncthreads();
#pragma unroll 4
    for (int j = 0; j < 128; j++) {
      float t0 = TxS[2 * rg][j], t1 = TxS[2 * rg + 1][j];
      const float* wp = &WS[j * 48 + 3 * cg];
      float w0 = wp[0], w1 = wp[1], w2 = wp[2];
      acc[0][0] += t0 * w0; acc[0][1] += t0 * w1; acc[0][2] += t0 * w2;
      acc[1][0] += t1 * w0; acc[1][1] += t1 * w1; acc[1][2] += t1 * w2;
    }
    __syncthreads();
  }
#pragma unroll
  for (int rr = 0; rr < 2; rr++) {
    int r = 2 * rg + rr;
#pragma unroll
    for (int cc = 0; cc < 3; cc++) {
      int c = 3 * cg + cc;
      float bias = c < 16 ? b3[c] : (c < 32 ? b6[c - 16] : b9[c - 32]);
      float v = acc[rr][cc] + bias;
      lo[r][c] = v;
      last_out[(size_t)(row0 + r) * 48 + c] = v;
    }
  }
  __syncthreads();
#pragma unroll
  for (int s = 0; s < 2; s++) {
    int idx = t + 256 * s;
    int r = idx >> 4, c = idx & 15;
    float lgt = blS[c];
#pragma unroll 8
    for (int j = 0; j < 48; j++) lgt += lo[r][j] * WlS[j * 16 + c];
    lg[r][c] = lgt;
  }
  __syncthreads();
#pragma unroll
  for (int s = 0; s < 2; s++) {
    int idx = t + 256 * s;
    int r = idx >> 4, c = idx & 15;
    float mx = lg[r][0];
#pragma unroll
    for (int j = 1; j < 16; j++) mx = fmaxf(mx, lg[r][j]);
    le[r][c] = __expf(lg[r][c] - mx);
  }
  __syncthreads();
#pragma unroll
  for (int s = 0; s < 2; s++) {
    int idx = t + 256 * s;
    int r = idx >> 4, c = idx & 15;
    float sum = 0.f;
#pragma unroll
    for (int j = 0; j < 16; j++) sum += le[r][j];
    x_out[(size_t)(row0 + r) * 16 + c] = le[r][c] / sum;
  }
}

// ---------------------------------------------------------------- misc copies + Wcat build
__global__ __launch_bounds__(256) void copy_kernel(
    const int* __restrict__ tr, const int* __restrict__ val,
    const float* __restrict__ x0, float* __restrict__ tr_out,
    float* __restrict__ val_out, float* __restrict__ x0_out,
    const float* __restrict__ W3, const float* __restrict__ W6,
    const float* __restrict__ W9, float* __restrict__ Wcat) {
  int i = blockIdx.x * 256 + threadIdx.x;
  if (i < 4000) tr_out[i] = (float)tr[i];
  if (i < 1000) val_out[i] = (float)val[i];
  if (i < NN * 64) x0_out[i] = x0[i];
  if (i < 9 * 128 * 48) {
    int c = i % 48;
    int j = (i / 48) % 128;
    int k = i / (48 * 128);
    float v = 0.f;
    if (c < 16) {
      if (k < 3) v = W3[(k * 128 + j) * 16 + c];
    } else if (c < 32) {
      if (k < 6) v = W6[(k * 128 + j) * 16 + (c - 16)];
    } else {
      v = W9[(k * 128 + j) * 16 + (c - 32)];
    }
    Wcat[i] = v;
  }
}

extern "C" void kernel_launch(void* const* d_in, const int* in_sizes, int n_in,
                              void* d_out, int out_size, void* d_ws, size_t ws_size,
                              hipStream_t stream) {
  const float* x5 = (const float*)d_in[0];
  const float* x0 = (const float*)d_in[1];
  const int* tr = (const int*)d_in[2];
  const int* val = (const int*)d_in[3];
  const float* W_gat = (const float*)d_in[4];
  const float* b_gat = (const float*)d_in[5];
  const float* W_lin = (const float*)d_in[6];
  const float* b_lin = (const float*)d_in[7];
  const float* W3 = (const float*)d_in[8];
  const float* b3 = (const float*)d_in[9];
  const float* W6 = (const float*)d_in[10];
  const float* b6 = (const float*)d_in[11];
  const float* W9 = (const float*)d_in[12];
  const float* b9 = (const float*)d_in[13];
  const float* Wl = (const float*)d_in[14];
  const float* bl = (const float*)d_in[15];

  float* out = (float*)d_out;
  float* x_out = out;
  float* tr_out = x_out + (size_t)NN * 16;
  float* val_out = tr_out + 4000;
  float* P = val_out + 1000;
  float* last_out = P + (size_t)NN * NN;
  float* x0_out = last_out + (size_t)NN * 48;

  char* w = (char*)d_ws;
  unsigned short* Sb = (unsigned short*)w;  w += (size_t)NN * NN * 2;
  float* Tx = (float*)w;                    w += (size_t)9 * NN * F1 * 4;
  float* partial = (float*)w;               w += (size_t)KSPLIT * NN * F1 * 4;
  unsigned short* XTa = (unsigned short*)w; w += (size_t)NN * F1 * 2;
  unsigned short* XTb = (unsigned short*)w; w += (size_t)NN * F1 * 2;
  float* hT = (float*)w;                    w += (size_t)6 * NN * 4;
  float* sq = (float*)w;                    w += (size_t)NN * 4;
  float* dinv = (float*)w;                  w += (size_t)NN * 4;
  float* Wcat = (float*)w;                  w += (size_t)9 * 128 * 48 * 4;

  prep_kernel<<<NN, 128, 0, stream>>>(x5, x0, W_gat, b_gat, W_lin, b_lin, hT, sq,
                                      Tx, XTa);
  prob_kernel<<<NN, 256, 0, stream>>>(hT, sq, P, dinv);
  smat_kernel<<<NN, 256, 0, stream>>>(hT, sq, dinv, Sb);
  copy_kernel<<<1536, 256, 0, stream>>>(tr, val, x0, tr_out, val_out, x0_out,
                                        W3, W6, W9, Wcat);

  unsigned short* xin = XTa;
  unsigned short* xout = XTb;
  for (int k = 1; k <= 8; k++) {
    gemm_kernel<<<768, 256, 0, stream>>>(Sb, xin, partial);
    const float4* pp = (const float4*)(Tx + (size_t)(k >= 2 ? k - 2 : 0) * NN * F1);
    finalize_kernel<<<192, 256, 0, stream>>>((const float4*)partial, pp,
                                             (float4*)(Tx + (size_t)k * NN * F1),
                                             xout, k >= 2 ? 1 : 0);
    unsigned short* tmp = xin; xin = xout; xout = tmp;
  }

  out_kernel<<<192, 256, 0, stream>>>(Tx, Wcat, b3, b6, b9, Wl, bl, x_out,
                                      last_out);
}

// Round 11
// 354.034 us; speedup vs baseline: 1.9364x; 1.2083x over previous
//
#include <hip/hip_runtime.h>
#include <hip/hip_fp8.h>

#define NN 6144
#define F1 128
#define KSPLIT 16
#define KC 384
#define BK 64
#define SSCALE 512.0f
#define SSCALE_INV (1.0f / 512.0f)

typedef __attribute__((ext_vector_type(4))) float f32x4;

__device__ __forceinline__ unsigned short f2bf(float f) {
  unsigned int u = __float_as_uint(f);
  unsigned int r = (u + 0x7fffu + ((u >> 16) & 1u)) >> 16;
  return (unsigned short)r;
}
__device__ __forceinline__ float bf2f(unsigned short u) {
  return __uint_as_float(((unsigned int)u) << 16);
}

__device__ __forceinline__ unsigned int pack4_fp8(float a, float b, float c, float d) {
#if __has_builtin(__builtin_amdgcn_cvt_pk_fp8_f32)
  int v = __builtin_amdgcn_cvt_pk_fp8_f32(a, b, 0, false);
  v = __builtin_amdgcn_cvt_pk_fp8_f32(c, d, v, true);
  return (unsigned int)v;
#else
  __hip_fp8_e4m3 qa(a), qb(b), qc(c), qd(d);
  return (unsigned)qa.__x | ((unsigned)qb.__x << 8) | ((unsigned)qc.__x << 16) |
         ((unsigned)qd.__x << 24);
#endif
}
__device__ __forceinline__ unsigned char f2fp8(float a) {
#if __has_builtin(__builtin_amdgcn_cvt_pk_fp8_f32)
  return (unsigned char)(__builtin_amdgcn_cvt_pk_fp8_f32(a, a, 0, false) & 0xFF);
#else
  __hip_fp8_e4m3 q(a);
  return q.__x;
#endif
}

// async global->LDS, 16B per lane; lds dest = base + lane*16 (wave-uniform base)
__device__ __forceinline__ void gload16(const void* g, void* l) {
  __builtin_amdgcn_global_load_lds(
      (const __attribute__((address_space(1))) unsigned int*)g,
      (__attribute__((address_space(3))) unsigned int*)l, 16, 0, 0);
}

// ---------------------------------------------------------------- prep
__global__ __launch_bounds__(128) void prep_kernel(
    const float* __restrict__ x5, const float* __restrict__ x0,
    const float* __restrict__ W_gat, const float* __restrict__ b_gat,
    const float* __restrict__ W_lin, const float* __restrict__ b_lin,
    float* __restrict__ hT, float* __restrict__ sq,
    float* __restrict__ Tx0, unsigned char* __restrict__ XT0) {
  int i = blockIdx.x;
  int t = threadIdx.x;
  __shared__ float xs[64];
  __shared__ float x5s[3];
  __shared__ float hs[6];
  if (t < 3) x5s[t] = x5[i * 3 + t];
  if (t < 64) xs[t] = x0[(size_t)i * 64 + t];
  __syncthreads();
  if (t < 6) {
    float a = b_gat[t];
#pragma unroll
    for (int k = 0; k < 3; k++) a += x5s[k] * W_gat[k * 6 + t];
    a = fmaxf(a, 0.f);
    hs[t] = a;
    hT[(size_t)t * NN + i] = a;
  }
  __syncthreads();
  if (t == 0) {
    float s = 0.f;
#pragma unroll
    for (int k = 0; k < 6; k++) s += hs[k] * hs[k];
    sq[i] = s;
  }
  float a = b_lin[t];
#pragma unroll 16
  for (int k = 0; k < 64; k++) a += xs[k] * W_lin[k * 128 + t];
  a = fmaxf(a, 0.f);
  Tx0[(size_t)i * F1 + t] = a;
  XT0[(size_t)t * NN + i] = f2fp8(a);
}

// ---------------------------------------------------------------- prob
__global__ __launch_bounds__(256) void prob_kernel(
    const float* __restrict__ hT, const float* __restrict__ sq,
    float* __restrict__ P, float* __restrict__ dinv) {
  int i = blockIdx.x;
  int t = threadIdx.x;
  float h0 = hT[i], h1 = hT[NN + i], h2 = hT[2 * NN + i];
  float h3 = hT[3 * NN + i], h4 = hT[4 * NN + i], h5 = hT[5 * NN + i];
  float si = sq[i];
  float acc = 0.f;
  float* Pr = P + (size_t)i * NN;
  for (int j = t; j < NN; j += 256) {
    float dot = h0 * hT[j] + h1 * hT[NN + j] + h2 * hT[2 * NN + j] +
                h3 * hT[3 * NN + j] + h4 * hT[4 * NN + j] + h5 * hT[5 * NN + j];
    float d = si + sq[j] - 2.f * dot;
    float p = __expf(-0.5f * d);
    Pr[j] = p;
    if (j != i) acc += p;
  }
  __shared__ float red[256];
  red[t] = acc;
  __syncthreads();
  for (int s = 128; s > 0; s >>= 1) {
    if (t < s) red[t] += red[t + s];
    __syncthreads();
  }
  if (t == 0) {
    float deg = red[0];
    dinv[i] = deg > 0.f ? rsqrtf(deg) : 0.f;
  }
}

// ---------------------------------------------------------------- smat (fp8, scaled by 512)
__global__ __launch_bounds__(256) void smat_kernel(
    const float* __restrict__ hT, const float* __restrict__ sq,
    const float* __restrict__ dinv, unsigned int* __restrict__ S32) {
  int i = blockIdx.x;
  int t = threadIdx.x;
  float h0 = hT[i], h1 = hT[NN + i], h2 = hT[2 * NN + i];
  float h3 = hT[3 * NN + i], h4 = hT[4 * NN + i], h5 = hT[5 * NN + i];
  float si = sq[i];
  float dis = -SSCALE * dinv[i];
  unsigned int* Sr = S32 + (size_t)i * (NN / 4);
  for (int j4 = t; j4 < NN / 4; j4 += 256) {
    int j = j4 * 4;
    float4 qv = *(const float4*)(sq + j);
    float4 dj = *(const float4*)(dinv + j);
    float4 v0 = *(const float4*)(hT + j);
    float4 v1 = *(const float4*)(hT + NN + j);
    float4 v2 = *(const float4*)(hT + 2 * NN + j);
    float4 v3 = *(const float4*)(hT + 3 * NN + j);
    float4 v4 = *(const float4*)(hT + 4 * NN + j);
    float4 v5 = *(const float4*)(hT + 5 * NN + j);
    float s[4];
#pragma unroll
    for (int m = 0; m < 4; m++) {
      float dot = h0 * ((const float*)&v0)[m] + h1 * ((const float*)&v1)[m] +
                  h2 * ((const float*)&v2)[m] + h3 * ((const float*)&v3)[m] +
                  h4 * ((const float*)&v4)[m] + h5 * ((const float*)&v5)[m];
      float d = si + ((const float*)&qv)[m] - 2.f * dot;
      float p = __expf(-0.5f * d);
      s[m] = dis * p * ((const float*)&dj)[m];
      if (j + m == i) s[m] = 0.f;
    }
    Sr[j4] = pack4_fp8(s[0], s[1], s[2], s[3]);
  }
}

// ---------------------------------------------------------------- gemm (fp8, gload_lds, split-K)
// grid 768 = (48 mb x 16 ks), block 256 (4 waves 2x2); tile 128x128, BK=64 fp8.
// LDS [128][64B] linear; unit(16B)-XOR swizzle key = ((r&3)+((r>>2)&3))&3
// applied on BOTH the pre-swizzled global source and the ds_read address.
__global__ __launch_bounds__(256, 3) void gemm_kernel(
    const unsigned char* __restrict__ S, const unsigned char* __restrict__ XT,
    unsigned short* __restrict__ partial) {
  __shared__ unsigned char As[128 * 64];
  __shared__ unsigned char Bs[128 * 64];
  // bijective XCD swizzle: 768 = 8 XCDs x 96 -> each XCD owns 2 ks values
  int orig = blockIdx.x;
  int wgid = (orig & 7) * 96 + (orig >> 3);
  int mb = wgid % 48;
  int ks = wgid / 48;
  int t = threadIdx.x;
  int w = t >> 6, l = t & 63;
  int wr = w >> 1, wc = w & 1;
  int lr = l & 15, lg = l >> 4;
  int row0 = mb * 128;
  int k0 = ks * KC;

  // staging: call covers 16 rows x 4 units(16B); lane: r16 = l>>2, dest unit = l&3
  int r16 = l >> 2;
  int key = ((r16 & 3) + ((r16 >> 2) & 3)) & 3;
  int us = (l & 3) ^ key;
  const unsigned char* gA = S + (size_t)(row0 + w * 32 + r16) * NN + k0 + us * 16;
  const unsigned char* gB = XT + (size_t)(w * 32 + r16) * NN + k0 + us * 16;
  unsigned char* lA = As + (w * 32) * 64;
  unsigned char* lB = Bs + (w * 32) * 64;

  f32x4 acc[4][4];
#pragma unroll
  for (int a = 0; a < 4; a++)
#pragma unroll
    for (int b = 0; b < 4; b++) acc[a][b] = (f32x4){0.f, 0.f, 0.f, 0.f};

  for (int bk = 0; bk < KC; bk += BK) {
    gload16(gA + bk, lA);
    gload16(gA + (size_t)16 * NN + bk, lA + 16 * 64);
    gload16(gB + bk, lB);
    gload16(gB + (size_t)16 * NN + bk, lB + 16 * 64);
    __syncthreads();  // vmcnt(0) drain + barrier
#pragma unroll
    for (int kk2 = 0; kk2 < BK; kk2 += 32) {
      long af[4], bf[4];
#pragma unroll
      for (int i = 0; i < 4; i++) {
        int ra = wr * 64 + i * 16 + lr;
        int rb = wc * 64 + i * 16 + lr;
        int off = kk2 + lg * 8;
        int ka = ((ra & 3) + ((ra >> 2) & 3)) & 3;
        int kb = ((rb & 3) + ((rb >> 2) & 3)) & 3;
        int pa = ra * 64 + ((((off >> 4) ^ ka) << 4) | (off & 8));
        int pb = rb * 64 + ((((off >> 4) ^ kb) << 4) | (off & 8));
        af[i] = *(const long*)(&As[pa]);
        bf[i] = *(const long*)(&Bs[pb]);
      }
#pragma unroll
      for (int ar = 0; ar < 4; ar++)
#pragma unroll
        for (int bn = 0; bn < 4; bn++)
          acc[ar][bn] = __builtin_amdgcn_mfma_f32_16x16x32_fp8_fp8(
              af[ar], bf[bn], acc[ar][bn], 0, 0, 0);
    }
    __syncthreads();
  }

  // C/D layout: col = lane&15, row-in-16 = lg*4 + r ; partial stored bf16
  unsigned short* pbase = partial + (size_t)ks * NN * F1;
#pragma unroll
  for (int ar = 0; ar < 4; ar++) {
    int rowo = row0 + wr * 64 + ar * 16 + lg * 4;
#pragma unroll
    for (int bn = 0; bn < 4; bn++) {
      int colo = wc * 64 + bn * 16 + lr;
#pragma unroll
      for (int r = 0; r < 4; r++)
        pbase[(size_t)(rowo + r) * F1 + colo] = f2bf(acc[ar][bn][r]);
    }
  }
}

// ---------------------------------------------------------------- finalize
// thread: rquad = t>>5 (4 rows), c4 = t&31 (4 features). bf16 partial sums in
// f32, 1/512 scale, recurrence vs f32 prevprev; writes Tx f32 + fp8 XT packs.
__global__ __launch_bounds__(256) void finalize_kernel(
    const unsigned short* __restrict__ partial, const float4* __restrict__ prevprev,
    float4* __restrict__ TxOut, unsigned int* __restrict__ XT8, int dsub) {
  const int TOT4 = NN * F1 / 4;
  int t = threadIdx.x;
  int rquad = t >> 5, c4 = t & 31;
  int row0 = blockIdx.x * 32 + rquad * 4;
  const ushort4* p4 = (const ushort4*)partial;
  float g[4][4];
#pragma unroll
  for (int rr = 0; rr < 4; rr++) {
    int fidx = (row0 + rr) * 32 + c4;
    float a0 = 0.f, a1 = 0.f, a2 = 0.f, a3 = 0.f;
#pragma unroll
    for (int s = 0; s < KSPLIT; s++) {
      ushort4 v = p4[(size_t)s * TOT4 + fidx];
      a0 += bf2f(v.x); a1 += bf2f(v.y); a2 += bf2f(v.z); a3 += bf2f(v.w);
    }
    a0 *= SSCALE_INV; a1 *= SSCALE_INV; a2 *= SSCALE_INV; a3 *= SSCALE_INV;
    if (dsub) {
      float4 q = prevprev[fidx];
      a0 = 2.f * a0 - q.x; a1 = 2.f * a1 - q.y;
      a2 = 2.f * a2 - q.z; a3 = 2.f * a3 - q.w;
    }
    float4 o; o.x = a0; o.y = a1; o.z = a2; o.w = a3;
    TxOut[fidx] = o;
    g[rr][0] = a0; g[rr][1] = a1; g[rr][2] = a2; g[rr][3] = a3;
  }
#pragma unroll
  for (int j = 0; j < 4; j++) {
    unsigned int pk = pack4_fp8(g[0][j], g[1][j], g[2][j], g[3][j]);
    XT8[(((size_t)(c4 * 4 + j)) * NN + row0) >> 2] = pk;
  }
}

// ---------------------------------------------------------------- epilogue
__global__ __launch_bounds__(256) void out_kernel(
    const float* __restrict__ Tx, const float* __restrict__ Wcat,
    const float* __restrict__ b3, const float* __restrict__ b6,
    const float* __restrict__ b9,
    const float* __restrict__ Wl, const float* __restrict__ bl,
    float* __restrict__ x_out, float* __restrict__ last_out) {
  __shared__ float WS[128 * 48];
  __shared__ float TxS[32][129];
  __shared__ float lo[32][48];
  __shared__ float lg[32][16];
  __shared__ float le[32][16];
  __shared__ float WlS[48 * 16];
  __shared__ float blS[16];
  int t = threadIdx.x;
  int row0 = blockIdx.x * 32;
  int rg = t >> 4;
  int cg = t & 15;
  float acc[2][3] = {{0.f, 0.f, 0.f}, {0.f, 0.f, 0.f}};
  for (int i = t; i < 768; i += 256) WlS[i] = Wl[i];
  if (t < 16) blS[t] = bl[t];
  for (int k = 0; k < 9; k++) {
    for (int i = t; i < 6144; i += 256) WS[i] = Wcat[k * 6144 + i];
    for (int i = t; i < 4096; i += 256) {
      int r = i >> 7, j = i & 127;
      TxS[r][j] = Tx[((size_t)k * NN + row0 + r) * F1 + j];
    }
    __syncthreads();
#pragma unroll 4
    for (int j = 0; j < 128; j++) {
      float t0 = TxS[2 * rg][j], t1 = TxS[2 * rg + 1][j];
      const float* wp = &WS[j * 48 + 3 * cg];
      float w0 = wp[0], w1 = wp[1], w2 = wp[2];
      acc[0][0] += t0 * w0; acc[0][1] += t0 * w1; acc[0][2] += t0 * w2;
      acc[1][0] += t1 * w0; acc[1][1] += t1 * w1; acc[1][2] += t1 * w2;
    }
    __syncthreads();
  }
#pragma unroll
  for (int rr = 0; rr < 2; rr++) {
    int r = 2 * rg + rr;
#pragma unroll
    for (int cc = 0; cc < 3; cc++) {
      int c = 3 * cg + cc;
      float bias = c < 16 ? b3[c] : (c < 32 ? b6[c - 16] : b9[c - 32]);
      float v = acc[rr][cc] + bias;
      lo[r][c] = v;
      last_out[(size_t)(row0 + r) * 48 + c] = v;
    }
  }
  __syncthreads();
#pragma unroll
  for (int s = 0; s < 2; s++) {
    int idx = t + 256 * s;
    int r = idx >> 4, c = idx & 15;
    float lgt = blS[c];
#pragma unroll 8
    for (int j = 0; j < 48; j++) lgt += lo[r][j] * WlS[j * 16 + c];
    lg[r][c] = lgt;
  }
  __syncthreads();
#pragma unroll
  for (int s = 0; s < 2; s++) {
    int idx = t + 256 * s;
    int r = idx >> 4, c = idx & 15;
    float mx = lg[r][0];
#pragma unroll
    for (int j = 1; j < 16; j++) mx = fmaxf(mx, lg[r][j]);
    le[r][c] = __expf(lg[r][c] - mx);
  }
  __syncthreads();
#pragma unroll
  for (int s = 0; s < 2; s++) {
    int idx = t + 256 * s;
    int r = idx >> 4, c = idx & 15;
    float sum = 0.f;
#pragma unroll
    for (int j = 0; j < 16; j++) sum += le[r][j];
    x_out[(size_t)(row0 + r) * 16 + c] = le[r][c] / sum;
  }
}

// ---------------------------------------------------------------- misc copies + Wcat build
__global__ __launch_bounds__(256) void copy_kernel(
    const int* __restrict__ tr, const int* __restrict__ val,
    const float* __restrict__ x0, float* __restrict__ tr_out,
    float* __restrict__ val_out, float* __restrict__ x0_out,
    const float* __restrict__ W3, const float* __restrict__ W6,
    const float* __restrict__ W9, float* __restrict__ Wcat) {
  int i = blockIdx.x * 256 + threadIdx.x;
  if (i < 4000) tr_out[i] = (float)tr[i];
  if (i < 1000) val_out[i] = (float)val[i];
  if (i < NN * 64) x0_out[i] = x0[i];
  if (i < 9 * 128 * 48) {
    int c = i % 48;
    int j = (i / 48) % 128;
    int k = i / (48 * 128);
    float v = 0.f;
    if (c < 16) {
      if (k < 3) v = W3[(k * 128 + j) * 16 + c];
    } else if (c < 32) {
      if (k < 6) v = W6[(k * 128 + j) * 16 + (c - 16)];
    } else {
      v = W9[(k * 128 + j) * 16 + (c - 32)];
    }
    Wcat[i] = v;
  }
}

extern "C" void kernel_launch(void* const* d_in, const int* in_sizes, int n_in,
                              void* d_out, int out_size, void* d_ws, size_t ws_size,
                              hipStream_t stream) {
  const float* x5 = (const float*)d_in[0];
  const float* x0 = (const float*)d_in[1];
  const int* tr = (const int*)d_in[2];
  const int* val = (const int*)d_in[3];
  const float* W_gat = (const float*)d_in[4];
  const float* b_gat = (const float*)d_in[5];
  const float* W_lin = (const float*)d_in[6];
  const float* b_lin = (const float*)d_in[7];
  const float* W3 = (const float*)d_in[8];
  const float* b3 = (const float*)d_in[9];
  const float* W6 = (const float*)d_in[10];
  const float* b6 = (const float*)d_in[11];
  const float* W9 = (const float*)d_in[12];
  const float* b9 = (const float*)d_in[13];
  const float* Wl = (const float*)d_in[14];
  const float* bl = (const float*)d_in[15];

  float* out = (float*)d_out;
  float* x_out = out;
  float* tr_out = x_out + (size_t)NN * 16;
  float* val_out = tr_out + 4000;
  float* P = val_out + 1000;
  float* last_out = P + (size_t)NN * NN;
  float* x0_out = last_out + (size_t)NN * 48;

  char* w = (char*)d_ws;
  unsigned char* Sb = (unsigned char*)w;    w += (size_t)NN * NN;
  float* Tx = (float*)w;                    w += (size_t)9 * NN * F1 * 4;
  unsigned short* partial = (unsigned short*)w; w += (size_t)KSPLIT * NN * F1 * 2;
  unsigned char* XTa = (unsigned char*)w;   w += (size_t)NN * F1;
  unsigned char* XTb = (unsigned char*)w;   w += (size_t)NN * F1;
  float* hT = (float*)w;                    w += (size_t)6 * NN * 4;
  float* sq = (float*)w;                    w += (size_t)NN * 4;
  float* dinv = (float*)w;                  w += (size_t)NN * 4;
  float* Wcat = (float*)w;                  w += (size_t)9 * 128 * 48 * 4;

  prep_kernel<<<NN, 128, 0, stream>>>(x5, x0, W_gat, b_gat, W_lin, b_lin, hT, sq,
                                      Tx, XTa);
  prob_kernel<<<NN, 256, 0, stream>>>(hT, sq, P, dinv);
  smat_kernel<<<NN, 256, 0, stream>>>(hT, sq, dinv, (unsigned int*)Sb);
  copy_kernel<<<1536, 256, 0, stream>>>(tr, val, x0, tr_out, val_out, x0_out,
                                        W3, W6, W9, Wcat);

  unsigned char* xin = XTa;
  unsigned char* xout = XTb;
  for (int k = 1; k <= 8; k++) {
    gemm_kernel<<<768, 256, 0, stream>>>(Sb, xin, partial);
    const float4* pp = (const float4*)(Tx + (size_t)(k >= 2 ? k - 2 : 0) * NN * F1);
    finalize_kernel<<<192, 256, 0, stream>>>(partial, pp,
                                             (float4*)(Tx + (size_t)k * NN * F1),
                                             (unsigned int*)xout, k >= 2 ? 1 : 0);
    unsigned char* tmp = xin; xin = xout; xout = tmp;
  }

  out_kernel<<<192, 256, 0, stream>>>(Tx, Wcat, b3, b6, b9, Wl, bl, x_out,
                                      last_out);
}

// Round 12
// 350.013 us; speedup vs baseline: 1.9586x; 1.0115x over previous
//
#include <hip/hip_runtime.h>
#include <hip/hip_fp8.h>

#define NN 6144
#define F1 128
#define KSPLIT 16
#define KC 384
#define BK 64
#define NSTEPS (KC / BK)
#define SSCALE 512.0f
#define SSCALE_INV (1.0f / 512.0f)

typedef __attribute__((ext_vector_type(4))) float f32x4;

__device__ __forceinline__ unsigned short f2bf(float f) {
  unsigned int u = __float_as_uint(f);
  unsigned int r = (u + 0x7fffu + ((u >> 16) & 1u)) >> 16;
  return (unsigned short)r;
}
__device__ __forceinline__ float bf2f(unsigned short u) {
  return __uint_as_float(((unsigned int)u) << 16);
}

__device__ __forceinline__ unsigned int pack4_fp8(float a, float b, float c, float d) {
#if __has_builtin(__builtin_amdgcn_cvt_pk_fp8_f32)
  int v = __builtin_amdgcn_cvt_pk_fp8_f32(a, b, 0, false);
  v = __builtin_amdgcn_cvt_pk_fp8_f32(c, d, v, true);
  return (unsigned int)v;
#else
  __hip_fp8_e4m3 qa(a), qb(b), qc(c), qd(d);
  return (unsigned)qa.__x | ((unsigned)qb.__x << 8) | ((unsigned)qc.__x << 16) |
         ((unsigned)qd.__x << 24);
#endif
}
__device__ __forceinline__ unsigned char f2fp8(float a) {
#if __has_builtin(__builtin_amdgcn_cvt_pk_fp8_f32)
  return (unsigned char)(__builtin_amdgcn_cvt_pk_fp8_f32(a, a, 0, false) & 0xFF);
#else
  __hip_fp8_e4m3 q(a);
  return q.__x;
#endif
}

// async global->LDS, 16B per lane; lds dest = base + lane*16 (wave-uniform base)
__device__ __forceinline__ void gload16(const void* g, void* l) {
  __builtin_amdgcn_global_load_lds(
      (const __attribute__((address_space(1))) unsigned int*)g,
      (__attribute__((address_space(3))) unsigned int*)l, 16, 0, 0);
}

// ---------------------------------------------------------------- prep
__global__ __launch_bounds__(128) void prep_kernel(
    const float* __restrict__ x5, const float* __restrict__ x0,
    const float* __restrict__ W_gat, const float* __restrict__ b_gat,
    const float* __restrict__ W_lin, const float* __restrict__ b_lin,
    float* __restrict__ hT, float* __restrict__ sq,
    float* __restrict__ Tx0, unsigned char* __restrict__ XT0) {
  int i = blockIdx.x;
  int t = threadIdx.x;
  __shared__ float xs[64];
  __shared__ float x5s[3];
  __shared__ float hs[6];
  if (t < 3) x5s[t] = x5[i * 3 + t];
  if (t < 64) xs[t] = x0[(size_t)i * 64 + t];
  __syncthreads();
  if (t < 6) {
    float a = b_gat[t];
#pragma unroll
    for (int k = 0; k < 3; k++) a += x5s[k] * W_gat[k * 6 + t];
    a = fmaxf(a, 0.f);
    hs[t] = a;
    hT[(size_t)t * NN + i] = a;
  }
  __syncthreads();
  if (t == 0) {
    float s = 0.f;
#pragma unroll
    for (int k = 0; k < 6; k++) s += hs[k] * hs[k];
    sq[i] = s;
  }
  float a = b_lin[t];
#pragma unroll 16
  for (int k = 0; k < 64; k++) a += xs[k] * W_lin[k * 128 + t];
  a = fmaxf(a, 0.f);
  Tx0[(size_t)i * F1 + t] = a;
  XT0[(size_t)t * NN + i] = f2fp8(a);
}

// ---------------------------------------------------------------- prob
__global__ __launch_bounds__(256) void prob_kernel(
    const float* __restrict__ hT, const float* __restrict__ sq,
    float* __restrict__ P, float* __restrict__ dinv) {
  int i = blockIdx.x;
  int t = threadIdx.x;
  float h0 = hT[i], h1 = hT[NN + i], h2 = hT[2 * NN + i];
  float h3 = hT[3 * NN + i], h4 = hT[4 * NN + i], h5 = hT[5 * NN + i];
  float si = sq[i];
  float acc = 0.f;
  float* Pr = P + (size_t)i * NN;
  for (int j = t; j < NN; j += 256) {
    float dot = h0 * hT[j] + h1 * hT[NN + j] + h2 * hT[2 * NN + j] +
                h3 * hT[3 * NN + j] + h4 * hT[4 * NN + j] + h5 * hT[5 * NN + j];
    float d = si + sq[j] - 2.f * dot;
    float p = __expf(-0.5f * d);
    Pr[j] = p;
    if (j != i) acc += p;
  }
  __shared__ float red[256];
  red[t] = acc;
  __syncthreads();
  for (int s = 128; s > 0; s >>= 1) {
    if (t < s) red[t] += red[t + s];
    __syncthreads();
  }
  if (t == 0) {
    float deg = red[0];
    dinv[i] = deg > 0.f ? rsqrtf(deg) : 0.f;
  }
}

// ---------------------------------------------------------------- smat (fp8, scaled by 512)
__global__ __launch_bounds__(256) void smat_kernel(
    const float* __restrict__ hT, const float* __restrict__ sq,
    const float* __restrict__ dinv, unsigned int* __restrict__ S32) {
  int i = blockIdx.x;
  int t = threadIdx.x;
  float h0 = hT[i], h1 = hT[NN + i], h2 = hT[2 * NN + i];
  float h3 = hT[3 * NN + i], h4 = hT[4 * NN + i], h5 = hT[5 * NN + i];
  float si = sq[i];
  float dis = -SSCALE * dinv[i];
  unsigned int* Sr = S32 + (size_t)i * (NN / 4);
  for (int j4 = t; j4 < NN / 4; j4 += 256) {
    int j = j4 * 4;
    float4 qv = *(const float4*)(sq + j);
    float4 dj = *(const float4*)(dinv + j);
    float4 v0 = *(const float4*)(hT + j);
    float4 v1 = *(const float4*)(hT + NN + j);
    float4 v2 = *(const float4*)(hT + 2 * NN + j);
    float4 v3 = *(const float4*)(hT + 3 * NN + j);
    float4 v4 = *(const float4*)(hT + 4 * NN + j);
    float4 v5 = *(const float4*)(hT + 5 * NN + j);
    float s[4];
#pragma unroll
    for (int m = 0; m < 4; m++) {
      float dot = h0 * ((const float*)&v0)[m] + h1 * ((const float*)&v1)[m] +
                  h2 * ((const float*)&v2)[m] + h3 * ((const float*)&v3)[m] +
                  h4 * ((const float*)&v4)[m] + h5 * ((const float*)&v5)[m];
      float d = si + ((const float*)&qv)[m] - 2.f * dot;
      float p = __expf(-0.5f * d);
      s[m] = dis * p * ((const float*)&dj)[m];
      if (j + m == i) s[m] = 0.f;
    }
    Sr[j4] = pack4_fp8(s[0], s[1], s[2], s[3]);
  }
}

// ---------------------------------------------------------------- gemm (fp8, dbuf gload_lds)
// grid 768 = (48 mb x 16 ks), block 256 (4 waves 2x2); tile 128x128, BK=64 fp8.
// T3-minimum 2-phase: STAGE(next) issued BEFORE compute(cur); single
// vmcnt(0)+barrier per step lands after compute -> latency hidden.
__global__ __launch_bounds__(256, 3) void gemm_kernel(
    const unsigned char* __restrict__ S, const unsigned char* __restrict__ XT,
    unsigned short* __restrict__ partial) {
  __shared__ unsigned char As[2][128 * 64];
  __shared__ unsigned char Bs[2][128 * 64];
  // bijective XCD swizzle: 768 = 8 XCDs x 96
  int orig = blockIdx.x;
  int wgid = (orig & 7) * 96 + (orig >> 3);
  int mb = wgid % 48;
  int ks = wgid / 48;
  int t = threadIdx.x;
  int w = t >> 6, l = t & 63;
  int wr = w >> 1, wc = w & 1;
  int lr = l & 15, lg = l >> 4;
  int row0 = mb * 128;
  int k0 = ks * KC;

  // staging: call covers 16 rows x 4 units(16B); lane: r16 = l>>2, dest unit = l&3
  int r16 = l >> 2;
  int key = ((r16 & 3) + ((r16 >> 2) & 3)) & 3;
  int us = (l & 3) ^ key;
  const unsigned char* gA = S + (size_t)(row0 + w * 32 + r16) * NN + k0 + us * 16;
  const unsigned char* gB = XT + (size_t)(w * 32 + r16) * NN + k0 + us * 16;
  int lofs = (w * 32) * 64;

  f32x4 acc[4][4];
#pragma unroll
  for (int a = 0; a < 4; a++)
#pragma unroll
    for (int b = 0; b < 4; b++) acc[a][b] = (f32x4){0.f, 0.f, 0.f, 0.f};

#define STAGE(buf, bk)                                        \
  do {                                                        \
    gload16(gA + (bk), &As[buf][lofs]);                       \
    gload16(gA + (size_t)16 * NN + (bk), &As[buf][lofs + 16 * 64]); \
    gload16(gB + (bk), &Bs[buf][lofs]);                       \
    gload16(gB + (size_t)16 * NN + (bk), &Bs[buf][lofs + 16 * 64]); \
  } while (0)

  STAGE(0, 0);
  __syncthreads();  // drain prologue
  int cur = 0;
  for (int step = 0; step < NSTEPS; step++) {
    if (step + 1 < NSTEPS) STAGE(cur ^ 1, (step + 1) * BK);
#pragma unroll
    for (int kk2 = 0; kk2 < BK; kk2 += 32) {
      long af[4], bf[4];
#pragma unroll
      for (int i = 0; i < 4; i++) {
        int ra = wr * 64 + i * 16 + lr;
        int rb = wc * 64 + i * 16 + lr;
        int off = kk2 + lg * 8;
        int ka = ((ra & 3) + ((ra >> 2) & 3)) & 3;
        int kb = ((rb & 3) + ((rb >> 2) & 3)) & 3;
        int pa = ra * 64 + ((((off >> 4) ^ ka) << 4) | (off & 8));
        int pb = rb * 64 + ((((off >> 4) ^ kb) << 4) | (off & 8));
        af[i] = *(const long*)(&As[cur][pa]);
        bf[i] = *(const long*)(&Bs[cur][pb]);
      }
#pragma unroll
      for (int ar = 0; ar < 4; ar++)
#pragma unroll
        for (int bn = 0; bn < 4; bn++)
          acc[ar][bn] = __builtin_amdgcn_mfma_f32_16x16x32_fp8_fp8(
              af[ar], bf[bn], acc[ar][bn], 0, 0, 0);
    }
    __syncthreads();  // drains next-tile loads (vmcnt0) + barrier
    cur ^= 1;
  }
#undef STAGE

  // C/D layout: col = lane&15, row-in-16 = lg*4 + r ; partial stored bf16
  unsigned short* pbase = partial + (size_t)ks * NN * F1;
#pragma unroll
  for (int ar = 0; ar < 4; ar++) {
    int rowo = row0 + wr * 64 + ar * 16 + lg * 4;
#pragma unroll
    for (int bn = 0; bn < 4; bn++) {
      int colo = wc * 64 + bn * 16 + lr;
#pragma unroll
      for (int r = 0; r < 4; r++)
        pbase[(size_t)(rowo + r) * F1 + colo] = f2bf(acc[ar][bn][r]);
    }
  }
}

// ---------------------------------------------------------------- finalize
__global__ __launch_bounds__(256) void finalize_kernel(
    const unsigned short* __restrict__ partial, const float4* __restrict__ prevprev,
    float4* __restrict__ TxOut, unsigned int* __restrict__ XT8, int dsub) {
  const int TOT4 = NN * F1 / 4;
  int t = threadIdx.x;
  int rquad = t >> 5, c4 = t & 31;
  int row0 = blockIdx.x * 32 + rquad * 4;
  const ushort4* p4 = (const ushort4*)partial;
  float g[4][4];
#pragma unroll
  for (int rr = 0; rr < 4; rr++) {
    int fidx = (row0 + rr) * 32 + c4;
    float a0 = 0.f, a1 = 0.f, a2 = 0.f, a3 = 0.f;
#pragma unroll
    for (int s = 0; s < KSPLIT; s++) {
      ushort4 v = p4[(size_t)s * TOT4 + fidx];
      a0 += bf2f(v.x); a1 += bf2f(v.y); a2 += bf2f(v.z); a3 += bf2f(v.w);
    }
    a0 *= SSCALE_INV; a1 *= SSCALE_INV; a2 *= SSCALE_INV; a3 *= SSCALE_INV;
    if (dsub) {
      float4 q = prevprev[fidx];
      a0 = 2.f * a0 - q.x; a1 = 2.f * a1 - q.y;
      a2 = 2.f * a2 - q.z; a3 = 2.f * a3 - q.w;
    }
    float4 o; o.x = a0; o.y = a1; o.z = a2; o.w = a3;
    TxOut[fidx] = o;
    g[rr][0] = a0; g[rr][1] = a1; g[rr][2] = a2; g[rr][3] = a3;
  }
#pragma unroll
  for (int j = 0; j < 4; j++) {
    unsigned int pk = pack4_fp8(g[0][j], g[1][j], g[2][j], g[3][j]);
    XT8[(((size_t)(c4 * 4 + j)) * NN + row0) >> 2] = pk;
  }
}

// ---------------------------------------------------------------- epilogue
__global__ __launch_bounds__(256) void out_kernel(
    const float* __restrict__ Tx, const float* __restrict__ Wcat,
    const float* __restrict__ b3, const float* __restrict__ b6,
    const float* __restrict__ b9,
    const float* __restrict__ Wl, const float* __restrict__ bl,
    float* __restrict__ x_out, float* __restrict__ last_out) {
  __shared__ float WS[128 * 48];
  __shared__ float TxS[32][129];
  __shared__ float lo[32][48];
  __shared__ float lg[32][16];
  __shared__ float le[32][16];
  __shared__ float WlS[48 * 16];
  __shared__ float blS[16];
  int t = threadIdx.x;
  int row0 = blockIdx.x * 32;
  int rg = t >> 4;
  int cg = t & 15;
  float acc[2][3] = {{0.f, 0.f, 0.f}, {0.f, 0.f, 0.f}};
  for (int i = t; i < 768; i += 256) WlS[i] = Wl[i];
  if (t < 16) blS[t] = bl[t];
  for (int k = 0; k < 9; k++) {
    for (int i = t; i < 6144; i += 256) WS[i] = Wcat[k * 6144 + i];
    for (int i = t; i < 4096; i += 256) {
      int r = i >> 7, j = i & 127;
      TxS[r][j] = Tx[((size_t)k * NN + row0 + r) * F1 + j];
    }
    __syncthreads();
#pragma unroll 4
    for (int j = 0; j < 128; j++) {
      float t0 = TxS[2 * rg][j], t1 = TxS[2 * rg + 1][j];
      const float* wp = &WS[j * 48 + 3 * cg];
      float w0 = wp[0], w1 = wp[1], w2 = wp[2];
      acc[0][0] += t0 * w0; acc[0][1] += t0 * w1; acc[0][2] += t0 * w2;
      acc[1][0] += t1 * w0; acc[1][1] += t1 * w1; acc[1][2] += t1 * w2;
    }
    __syncthreads();
  }
#pragma unroll
  for (int rr = 0; rr < 2; rr++) {
    int r = 2 * rg + rr;
#pragma unroll
    for (int cc = 0; cc < 3; cc++) {
      int c = 3 * cg + cc;
      float bias = c < 16 ? b3[c] : (c < 32 ? b6[c - 16] : b9[c - 32]);
      float v = acc[rr][cc] + bias;
      lo[r][c] = v;
      last_out[(size_t)(row0 + r) * 48 + c] = v;
    }
  }
  __syncthreads();
#pragma unroll
  for (int s = 0; s < 2; s++) {
    int idx = t + 256 * s;
    int r = idx >> 4, c = idx & 15;
    float lgt = blS[c];
#pragma unroll 8
    for (int j = 0; j < 48; j++) lgt += lo[r][j] * WlS[j * 16 + c];
    lg[r][c] = lgt;
  }
  __syncthreads();
#pragma unroll
  for (int s = 0; s < 2; s++) {
    int idx = t + 256 * s;
    int r = idx >> 4, c = idx & 15;
    float mx = lg[r][0];
#pragma unroll
    for (int j = 1; j < 16; j++) mx = fmaxf(mx, lg[r][j]);
    le[r][c] = __expf(lg[r][c] - mx);
  }
  __syncthreads();
#pragma unroll
  for (int s = 0; s < 2; s++) {
    int idx = t + 256 * s;
    int r = idx >> 4, c = idx & 15;
    float sum = 0.f;
#pragma unroll
    for (int j = 0; j < 16; j++) sum += le[r][j];
    x_out[(size_t)(row0 + r) * 16 + c] = le[r][c] / sum;
  }
}

// ---------------------------------------------------------------- misc copies + Wcat build
__global__ __launch_bounds__(256) void copy_kernel(
    const int* __restrict__ tr, const int* __restrict__ val,
    const float* __restrict__ x0, float* __restrict__ tr_out,
    float* __restrict__ val_out, float* __restrict__ x0_out,
    const float* __restrict__ W3, const float* __restrict__ W6,
    const float* __restrict__ W9, float* __restrict__ Wcat) {
  int i = blockIdx.x * 256 + threadIdx.x;
  if (i < 4000) tr_out[i] = (float)tr[i];
  if (i < 1000) val_out[i] = (float)val[i];
  if (i < NN * 64) x0_out[i] = x0[i];
  if (i < 9 * 128 * 48) {
    int c = i % 48;
    int j = (i / 48) % 128;
    int k = i / (48 * 128);
    float v = 0.f;
    if (c < 16) {
      if (k < 3) v = W3[(k * 128 + j) * 16 + c];
    } else if (c < 32) {
      if (k < 6) v = W6[(k * 128 + j) * 16 + (c - 16)];
    } else {
      v = W9[(k * 128 + j) * 16 + (c - 32)];
    }
    Wcat[i] = v;
  }
}

extern "C" void kernel_launch(void* const* d_in, const int* in_sizes, int n_in,
                              void* d_out, int out_size, void* d_ws, size_t ws_size,
                              hipStream_t stream) {
  const float* x5 = (const float*)d_in[0];
  const float* x0 = (const float*)d_in[1];
  const int* tr = (const int*)d_in[2];
  const int* val = (const int*)d_in[3];
  const float* W_gat = (const float*)d_in[4];
  const float* b_gat = (const float*)d_in[5];
  const float* W_lin = (const float*)d_in[6];
  const float* b_lin = (const float*)d_in[7];
  const float* W3 = (const float*)d_in[8];
  const float* b3 = (const float*)d_in[9];
  const float* W6 = (const float*)d_in[10];
  const float* b6 = (const float*)d_in[11];
  const float* W9 = (const float*)d_in[12];
  const float* b9 = (const float*)d_in[13];
  const float* Wl = (const float*)d_in[14];
  const float* bl = (const float*)d_in[15];

  float* out = (float*)d_out;
  float* x_out = out;
  float* tr_out = x_out + (size_t)NN * 16;
  float* val_out = tr_out + 4000;
  float* P = val_out + 1000;
  float* last_out = P + (size_t)NN * NN;
  float* x0_out = last_out + (size_t)NN * 48;

  char* w = (char*)d_ws;
  unsigned char* Sb = (unsigned char*)w;    w += (size_t)NN * NN;
  float* Tx = (float*)w;                    w += (size_t)9 * NN * F1 * 4;
  unsigned short* partial = (unsigned short*)w; w += (size_t)KSPLIT * NN * F1 * 2;
  unsigned char* XTa = (unsigned char*)w;   w += (size_t)NN * F1;
  unsigned char* XTb = (unsigned char*)w;   w += (size_t)NN * F1;
  float* hT = (float*)w;                    w += (size_t)6 * NN * 4;
  float* sq = (float*)w;                    w += (size_t)NN * 4;
  float* dinv = (float*)w;                  w += (size_t)NN * 4;
  float* Wcat = (float*)w;                  w += (size_t)9 * 128 * 48 * 4;

  prep_kernel<<<NN, 128, 0, stream>>>(x5, x0, W_gat, b_gat, W_lin, b_lin, hT, sq,
                                      Tx, XTa);
  prob_kernel<<<NN, 256, 0, stream>>>(hT, sq, P, dinv);
  smat_kernel<<<NN, 256, 0, stream>>>(hT, sq, dinv, (unsigned int*)Sb);
  copy_kernel<<<1536, 256, 0, stream>>>(tr, val, x0, tr_out, val_out, x0_out,
                                        W3, W6, W9, Wcat);

  unsigned char* xin = XTa;
  unsigned char* xout = XTb;
  for (int k = 1; k <= 8; k++) {
    gemm_kernel<<<768, 256, 0, stream>>>(Sb, xin, partial);
    const float4* pp = (const float4*)(Tx + (size_t)(k >= 2 ? k - 2 : 0) * NN * F1);
    finalize_kernel<<<192, 256, 0, stream>>>(partial, pp,
                                             (float4*)(Tx + (size_t)k * NN * F1),
                                             (unsigned int*)xout, k >= 2 ? 1 : 0);
    unsigned char* tmp = xin; xin = xout; xout = tmp;
  }

  out_kernel<<<192, 256, 0, stream>>>(Tx, Wcat, b3, b6, b9, Wl, bl, x_out,
                                      last_out);
}